// Round 12
// baseline (420.130 us; speedup 1.0000x reference)
//
#include <hip/hip_runtime.h>
#include <math.h>

// ---------------------------------------------------------------------------
// Fused GAT(4 heads, 32 ch) + GCN + gated fusion + residual + LayerNorm
// N=50000, D=128, E=800000 (+N self-loops folded analytically).
// Round 12: launch consolidation (8 -> 4 + memset):
//   K1 prep||hist, K2 single-block scan, K3 scatter||MFMA-GEMM (32KB LDS
//   halves for occupancy), K4 gather (4-way unroll reverted from R11's
//   8-way VGPR/occupancy regression).
// ---------------------------------------------------------------------------

typedef __attribute__((ext_vector_type(8))) short    bf16x8;
typedef __attribute__((ext_vector_type(4))) float    f32x4;
typedef __attribute__((ext_vector_type(8))) unsigned short u16x8;

__device__ __forceinline__ unsigned short f2bf(float f) {
    unsigned int u = __float_as_uint(f);
    u += 0x7fffu + ((u >> 16) & 1u);          // round-to-nearest-even
    return (unsigned short)(u >> 16);
}
__device__ __forceinline__ float bfhi(unsigned int u) {   // high ushort -> float
    return __uint_as_float(u & 0xffff0000u);
}
__device__ __forceinline__ float bflo(unsigned int u) {   // low ushort -> float
    return __uint_as_float(u << 16);
}

// K1: blocks [0,16): Wt[256][128] bf16 transpose-pack (n<128 -> gat_W else gcn_W)
//     blocks [16,..): histogram of incoming-edge counts (grid-stride)
__global__ __launch_bounds__(256) void k_prep_hist(
    const float* __restrict__ Wg, const float* __restrict__ Wc,
    unsigned short* __restrict__ wt, const int* __restrict__ dst,
    int* __restrict__ counts, int E)
{
    const int t = threadIdx.x;
    if (blockIdx.x < 16) {
        const int g = blockIdx.x * 256 + t;             // 0..4095
        const int nn = g >> 4;
        const int k0 = (g & 15) * 8;
        const float* Wsrc = (nn < 128) ? (Wg + nn) : (Wc + (nn - 128));
        u16x8 u;
        #pragma unroll
        for (int j = 0; j < 8; ++j) u[j] = f2bf(Wsrc[(size_t)(k0 + j) * 128]);
        *reinterpret_cast<u16x8*>(wt + (size_t)g * 8) = u;
        return;
    }
    int i = (blockIdx.x - 16) * 256 + t;
    const int stride = (gridDim.x - 16) * 256;
    for (; i < E; i += stride) atomicAdd(&counts[dst[i]], 1);
}

// K2: single-block scan: rowptr (exclusive), cursor copy, dinv = rsqrt(1+deg)
__global__ __launch_bounds__(1024) void k_scan(
    const int* __restrict__ counts, int* __restrict__ rowptr,
    int* __restrict__ cursor, float* __restrict__ dinv, int n)
{
    __shared__ int sh[1024];
    const int t = threadIdx.x;
    const int CH = (n + 1023) >> 10;                    // 49 for n=50000
    const int i0 = t * CH;
    int s = 0;
    for (int k = 0; k < CH; ++k) {
        const int i = i0 + k;
        if (i < n) s += counts[i];
    }
    sh[t] = s;
    __syncthreads();
    for (int off = 1; off < 1024; off <<= 1) {
        const int u = (t >= off) ? sh[t - off] : 0;
        __syncthreads();
        sh[t] += u;
        __syncthreads();
    }
    int run = sh[t] - s;                                // exclusive prefix
    for (int k = 0; k < CH; ++k) {
        const int i = i0 + k;
        if (i < n) {
            const int v = counts[i];
            rowptr[i] = run;
            cursor[i] = run;
            dinv[i] = rsqrtf((float)(1 + v));
            run += v;
        }
    }
    if (t == 1023) rowptr[n] = sh[1023];
}

// K3: blocks [0,scatBlocks): CSR scatter (grid-stride, atomic cursor)
//     blocks [scatBlocks,..): MFMA GEMM halves -> interleaved bf16 pk + logits
// Each GEMM block: 64 rows x 128 cols (half=0 -> h / gat_W cols, half=1 ->
// g / gcn_W cols, pre-scaled by dinv). 32 KB LDS (XOR-swizzled Wt half)
// -> 5 blocks/CU so co-resident scatter blocks keep decent occupancy.
// pk layout per row (256 u16): h pair p at {4p,4p+1}, g*dinv pair p at
// {4p+2,4p+3}; lane l of k_fused reads uint2 at row*64+l.
__global__ __launch_bounds__(256) void k_combo_scatter(
    const float* __restrict__ x, const unsigned short* __restrict__ wt,
    const float* __restrict__ att_src, const float* __restrict__ att_dst,
    const float* __restrict__ dinv, const int* __restrict__ src,
    const int* __restrict__ dst, int* __restrict__ cursor,
    int* __restrict__ esorted, unsigned short* __restrict__ pk,
    float* __restrict__ a_src, float* __restrict__ a_dst,
    int n, int E, int scatBlocks)
{
    __shared__ unsigned short wlds[16384];              // 32 KB
    const int t = threadIdx.x;

    if (blockIdx.x < scatBlocks) {
        int i = blockIdx.x * 256 + t;
        const int stride = scatBlocks * 256;
        for (; i < E; i += stride) {
            const int p = atomicAdd(&cursor[dst[i]], 1);
            esorted[p] = src[i];
        }
        return;
    }

    const int gb = blockIdx.x - scatBlocks;
    const int half = gb & 1;                  // 0: h cols / 1: g cols
    const int gtile = gb >> 1;

    // ---- stage this half's Wt rows -> LDS (swizzled) ----
    char* lbase = (char*)wlds;
    #pragma unroll
    for (int i2 = 0; i2 < 8; ++i2) {
        const int ch = i2 * 256 + t;                    // 16B chunk, 0..2047
        const int nn = ch >> 4;                         // local row 0..127
        const int off = (ch & 15) * 16;
        const int byte = (nn * 256 + off) ^ ((nn & 7) << 4);
        *reinterpret_cast<u16x8*>(lbase + byte) =
            *reinterpret_cast<const u16x8*>(
                wt + (size_t)(half * 128 + nn) * 128 + (ch & 15) * 8);
    }
    __syncthreads();

    const int l = t & 63;
    const int row0 = gtile * 64 + (t >> 6) * 16;        // wave's 16 rows
    const int arow = row0 + (l & 15);
    const bool av = arow < n;
    const float* xp = x + (size_t)arow * 128 + (l >> 4) * 8;

    // ---- A fragments straight from global (fp32 -> bf16 in-register) ----
    bf16x8 afr[4];
    #pragma unroll
    for (int ks = 0; ks < 4; ++ks) {
        float4 u0 = av ? *reinterpret_cast<const float4*>(xp + ks * 32)
                       : make_float4(0.f, 0.f, 0.f, 0.f);
        float4 u1 = av ? *reinterpret_cast<const float4*>(xp + ks * 32 + 4)
                       : make_float4(0.f, 0.f, 0.f, 0.f);
        bf16x8 a;
        a[0] = (short)f2bf(u0.x); a[1] = (short)f2bf(u0.y);
        a[2] = (short)f2bf(u0.z); a[3] = (short)f2bf(u0.w);
        a[4] = (short)f2bf(u1.x); a[5] = (short)f2bf(u1.y);
        a[6] = (short)f2bf(u1.z); a[7] = (short)f2bf(u1.w);
        afr[ks] = a;
    }

    // ---- MFMA: 8 N-tiles x 4 K-steps ----
    f32x4 acc[8];
    #pragma unroll
    for (int ni = 0; ni < 8; ++ni) acc[ni] = (f32x4){0.f, 0.f, 0.f, 0.f};

    const int bco = (l & 15) * 256 + (l >> 4) * 16;
    const int bxo = (l & 7) << 4;
    #pragma unroll
    for (int ks = 0; ks < 4; ++ks) {
        #pragma unroll
        for (int ni = 0; ni < 8; ++ni) {
            const int byte = ((ni * 16) * 256 + bco + ks * 64) ^ bxo;
            const bf16x8 b = *reinterpret_cast<const bf16x8*>(lbase + byte);
            acc[ni] = __builtin_amdgcn_mfma_f32_16x16x32_bf16(afr[ks], b, acc[ni], 0, 0, 0);
        }
    }

    const int m = l & 15;
    const int mo = m & 1;

    if (half == 0) {
        // ---- attention logits (h cols); C: col=ni*16+m, row=row0+(l>>4)*4+q
        float ps[4][4], pd[4][4];
        #pragma unroll
        for (int h = 0; h < 4; ++h)
            #pragma unroll
            for (int q = 0; q < 4; ++q) { ps[h][q] = 0.f; pd[h][q] = 0.f; }
        #pragma unroll
        for (int ni = 0; ni < 8; ++ni) {
            const float as = att_src[ni * 16 + m];
            const float ad = att_dst[ni * 16 + m];
            #pragma unroll
            for (int q = 0; q < 4; ++q) {
                ps[ni >> 1][q] += acc[ni][q] * as;
                pd[ni >> 1][q] += acc[ni][q] * ad;
            }
        }
        #pragma unroll
        for (int h = 0; h < 4; ++h) {
            #pragma unroll
            for (int q = 0; q < 4; ++q) {
                float v = ps[h][q];
                v += __shfl_xor(v, 1); v += __shfl_xor(v, 2);
                v += __shfl_xor(v, 4); v += __shfl_xor(v, 8);
                ps[h][q] = v;
                float u = pd[h][q];
                u += __shfl_xor(u, 1); u += __shfl_xor(u, 2);
                u += __shfl_xor(u, 4); u += __shfl_xor(u, 8);
                pd[h][q] = u;
            }
        }
        if (m == 0) {
            #pragma unroll
            for (int q = 0; q < 4; ++q) {
                const int row = row0 + (l >> 4) * 4 + q;
                if (row < n) {
                    *reinterpret_cast<float4*>(a_src + (size_t)row * 4) =
                        make_float4(ps[0][q], ps[1][q], ps[2][q], ps[3][q]);
                    *reinterpret_cast<float4*>(a_dst + (size_t)row * 4) =
                        make_float4(pd[0][q], pd[1][q], pd[2][q], pd[3][q]);
                }
            }
        }
        // ---- pack h ----
        #pragma unroll
        for (int q = 0; q < 4; ++q) {
            const int row = row0 + (l >> 4) * 4 + q;
            if (row >= n) continue;
            unsigned short* pr = pk + (size_t)row * 256;
            #pragma unroll
            for (int ni = 0; ni < 8; ++ni) {
                const int c = ni * 16 + m;
                pr[2 * c - mo] = f2bf(acc[ni][q]);
            }
        }
    } else {
        // ---- pack g * dinv ----
        #pragma unroll
        for (int q = 0; q < 4; ++q) {
            const int row = row0 + (l >> 4) * 4 + q;
            if (row >= n) continue;
            const float dv = dinv[row];
            unsigned short* pr = pk + (size_t)row * 256;
            #pragma unroll
            for (int ni = 0; ni < 8; ++ni) {
                const int cp = ni * 16 + m;
                pr[2 * cp + 2 - mo] = f2bf(acc[ni][q] * dv);
            }
        }
    }
}

// K4: single-pass gather (deferred softmax norm) + gate + residual + LN
// wave per node; lane owns channels {2l, 2l+1}; 4-way unroll (R11's 8-way
// cost VGPR 24->40 and occupancy 70->53% -- net loss, reverted).
__global__ __launch_bounds__(256) void k_fused(
    const int* __restrict__ esorted, const int* __restrict__ rowptr,
    const uint2* __restrict__ pkv,
    const float* __restrict__ a_src, const float* __restrict__ a_dst,
    const float* __restrict__ dinv, const float* __restrict__ x,
    const float* __restrict__ gat_bias, const float* __restrict__ gcn_bias,
    const float* __restrict__ gate_W, const float* __restrict__ gate_b,
    const float* __restrict__ gamma, const float* __restrict__ beta,
    float* __restrict__ out, int n)
{
    const int lane = threadIdx.x & 63;
    const int node = blockIdx.x * 4 + (threadIdx.x >> 6);
    if (node >= n) return;

    const int head = lane >> 4;
    const float adh = a_dst[node * 4 + head];
    const int beg = rowptr[node], end = rowptr[node + 1];

    float acc0 = 0.f, acc1 = 0.f, accg0 = 0.f, accg1 = 0.f, ws = 0.f;

#define ELOAD(i) \
    const int s##i = esorted[j + i]; \
    const uint2 f##i = pkv[(size_t)s##i * 64 + lane]; \
    const float a##i = a_src[s##i * 4 + head];

#define EBODY(i) \
    { \
        float e = a##i + adh; e = e > 0.f ? e : 0.2f * e; \
        const float w = __expf(e); ws += w; \
        acc0  = fmaf(w, bflo(f##i.x), acc0); \
        acc1  = fmaf(w, bfhi(f##i.x), acc1); \
        accg0 += bflo(f##i.y); \
        accg1 += bfhi(f##i.y); \
    }

    int j = beg;
    for (; j + 4 <= end; j += 4) {
        ELOAD(0) ELOAD(1) ELOAD(2) ELOAD(3)
        EBODY(0) EBODY(1) EBODY(2) EBODY(3)
    }
    for (; j < end; ++j) {
        ELOAD(0)
        EBODY(0)
    }

    // self loop
    {
        const uint2 f = pkv[(size_t)node * 64 + lane];
        float e = a_src[node * 4 + head] + adh;
        e = e > 0.f ? e : 0.2f * e;
        const float w = __expf(e);
        ws += w;
        acc0  = fmaf(w, bflo(f.x), acc0);
        acc1  = fmaf(w, bfhi(f.x), acc1);
        accg0 += bflo(f.y);
        accg1 += bfhi(f.y);
    }
#undef ELOAD
#undef EBODY

    // ---- epilogue: gate softmax + fuse + residual + LayerNorm ----
    const float dvd = dinv[node];
    const float2 gb2 = *reinterpret_cast<const float2*>(gat_bias + 2 * lane);
    const float2 gc2 = *reinterpret_cast<const float2*>(gcn_bias + 2 * lane);
    const float iws = 1.f / ws;
    float ga0 = acc0 * iws + gb2.x;
    float ga1 = acc1 * iws + gb2.y;
    float gc0 = accg0 * dvd + gc2.x;
    float gc1 = accg1 * dvd + gc2.y;

    const float4 gwa = *reinterpret_cast<const float4*>(gate_W + 4 * lane);
    const float4 gwb = *reinterpret_cast<const float4*>(gate_W + 256 + 4 * lane);
    float z0 = ga0 * gwa.x + ga1 * gwa.z + gc0 * gwb.x + gc1 * gwb.z;
    float z1 = ga0 * gwa.y + ga1 * gwa.w + gc0 * gwb.y + gc1 * gwb.w;
    #pragma unroll
    for (int off = 32; off >= 1; off >>= 1) {
        z0 += __shfl_xor(z0, off);
        z1 += __shfl_xor(z1, off);
    }
    z0 += gate_b[0]; z1 += gate_b[1];
    float m = fmaxf(z0, z1);
    float ez0 = __expf(z0 - m), ez1 = __expf(z1 - m);
    float inv = 1.f / (ez0 + ez1);
    float g0 = ez0 * inv, g1 = ez1 * inv;

    const size_t nbase = (size_t)node * 128;
    const float2 xv = *reinterpret_cast<const float2*>(x + nbase + 2 * lane);
    float y0 = g0 * ga0 + g1 * gc0 + xv.x;
    float y1 = g0 * ga1 + g1 * gc1 + xv.y;

    float sum = y0 + y1;
    #pragma unroll
    for (int off = 32; off >= 1; off >>= 1) sum += __shfl_xor(sum, off);
    float mu = sum * (1.f / 128.f);
    float d0v = y0 - mu, d1v = y1 - mu;
    float sq = d0v * d0v + d1v * d1v;
    #pragma unroll
    for (int off = 32; off >= 1; off >>= 1) sq += __shfl_xor(sq, off);
    float r = rsqrtf(sq * (1.f / 128.f) + 1e-5f);

    const float2 gm = *reinterpret_cast<const float2*>(gamma + 2 * lane);
    const float2 bt = *reinterpret_cast<const float2*>(beta + 2 * lane);
    float2 o;
    o.x = d0v * r * gm.x + bt.x;
    o.y = d1v * r * gm.y + bt.y;
    *reinterpret_cast<float2*>(out + nbase + 2 * lane) = o;
}

extern "C" void kernel_launch(void* const* d_in, const int* in_sizes, int n_in,
                              void* d_out, int out_size, void* d_ws, size_t ws_size,
                              hipStream_t stream)
{
    const float* x        = (const float*)d_in[0];
    const float* gat_W    = (const float*)d_in[1];
    const float* att_src  = (const float*)d_in[2];
    const float* att_dst  = (const float*)d_in[3];
    const float* gat_bias = (const float*)d_in[4];
    const float* gcn_W    = (const float*)d_in[5];
    const float* gcn_bias = (const float*)d_in[6];
    const float* gate_W   = (const float*)d_in[7];
    const float* gate_b   = (const float*)d_in[8];
    const float* ln_gamma = (const float*)d_in[9];
    const float* ln_beta  = (const float*)d_in[10];
    const int*   edge     = (const int*)d_in[11];

    const int n = in_sizes[0] / 128;
    const int E = in_sizes[11] / 2;
    const int* src = edge;
    const int* dst = edge + E;

    char* w = (char*)d_ws;
    unsigned short* pk = (unsigned short*)w;  w += (size_t)n * 256 * 2;
    unsigned short* wt = (unsigned short*)w;  w += (size_t)256 * 128 * 2;
    float* a_src   = (float*)w;  w += (size_t)n * 4 * 4;
    float* a_dst   = (float*)w;  w += (size_t)n * 4 * 4;
    float* dinv    = (float*)w;  w += (size_t)n * 4;
    int*   counts  = (int*)w;    w += (size_t)n * 4;
    int*   rowptr  = (int*)w;    w += (size_t)(n + 1) * 4;
    int*   cursor  = (int*)w;    w += (size_t)n * 4;
    int*   esorted = (int*)w;    w += (size_t)E * 4;

    hipMemsetAsync(counts, 0, (size_t)n * 4, stream);

    const int histBlocks = 1024;
    const int scatBlocks = 1024;
    const int gemmBlocks = 2 * ((n + 63) / 64);     // 1564 half-blocks

    k_prep_hist<<<16 + histBlocks, 256, 0, stream>>>(gat_W, gcn_W, wt, dst, counts, E);
    k_scan<<<1, 1024, 0, stream>>>(counts, rowptr, cursor, dinv, n);
    k_combo_scatter<<<scatBlocks + gemmBlocks, 256, 0, stream>>>(
        x, wt, att_src, att_dst, dinv, src, dst, cursor, esorted,
        pk, a_src, a_dst, n, E, scatBlocks);
    k_fused<<<(n + 3) / 4, 256, 0, stream>>>(esorted, rowptr, (const uint2*)pk,
                                             a_src, a_dst, dinv, x, gat_bias, gcn_bias,
                                             gate_W, gate_b, ln_gamma, ln_beta,
                                             (float*)d_out, n);
}

// Round 15
// 273.740 us; speedup vs baseline: 1.5348x; 1.5348x over previous
//
#include <hip/hip_runtime.h>
#include <math.h>

// ---------------------------------------------------------------------------
// Fused GAT(4 heads, 32 ch) + GCN + gated fusion + residual + LayerNorm
// N=50000, D=128, E=800000 (+N self-loops folded analytically).
// Round 13 kernel, third submission (two GPU acquisition timeouts): revert
// R12's single-block scan (measured 151us disaster -- 1 CU serial walk)
// back to the 3-kernel multi-block scan; keep prep||hist,
// scatter||MFMA-GEMM fusion and 4-way k_fused for attribution.
// ---------------------------------------------------------------------------

typedef __attribute__((ext_vector_type(8))) short    bf16x8;
typedef __attribute__((ext_vector_type(4))) float    f32x4;
typedef __attribute__((ext_vector_type(8))) unsigned short u16x8;

__device__ __forceinline__ unsigned short f2bf(float f) {
    unsigned int u = __float_as_uint(f);
    u += 0x7fffu + ((u >> 16) & 1u);          // round-to-nearest-even
    return (unsigned short)(u >> 16);
}
__device__ __forceinline__ float bfhi(unsigned int u) {   // high ushort -> float
    return __uint_as_float(u & 0xffff0000u);
}
__device__ __forceinline__ float bflo(unsigned int u) {   // low ushort -> float
    return __uint_as_float(u << 16);
}

// K1: blocks [0,16): Wt[256][128] bf16 transpose-pack (n<128 -> gat_W else gcn_W)
//     blocks [16,..): histogram of incoming-edge counts (grid-stride)
__global__ __launch_bounds__(256) void k_prep_hist(
    const float* __restrict__ Wg, const float* __restrict__ Wc,
    unsigned short* __restrict__ wt, const int* __restrict__ dst,
    int* __restrict__ counts, int E)
{
    const int t = threadIdx.x;
    if (blockIdx.x < 16) {
        const int g = blockIdx.x * 256 + t;             // 0..4095
        const int nn = g >> 4;
        const int k0 = (g & 15) * 8;
        const float* Wsrc = (nn < 128) ? (Wg + nn) : (Wc + (nn - 128));
        u16x8 u;
        #pragma unroll
        for (int j = 0; j < 8; ++j) u[j] = f2bf(Wsrc[(size_t)(k0 + j) * 128]);
        *reinterpret_cast<u16x8*>(wt + (size_t)g * 8) = u;
        return;
    }
    int i = (blockIdx.x - 16) * 256 + t;
    const int stride = (gridDim.x - 16) * 256;
    for (; i < E; i += stride) atomicAdd(&counts[dst[i]], 1);
}

// K2a: per-256-chunk sums of counts  (multi-block -- measured fast R2-R11)
__global__ __launch_bounds__(256) void k_scan1(const int* __restrict__ counts,
                                               int* __restrict__ bsum, int n)
{
    __shared__ int sh[256];
    int t = threadIdx.x;
    int i = blockIdx.x * 256 + t;
    sh[t] = (i < n) ? counts[i] : 0;
    __syncthreads();
    #pragma unroll
    for (int off = 128; off >= 1; off >>= 1) {
        if (t < off) sh[t] += sh[t + off];
        __syncthreads();
    }
    if (t == 0) bsum[blockIdx.x] = sh[0];
}

// K2b: exclusive scan of block sums (nb <= 256), single block
__global__ __launch_bounds__(256) void k_scan2(int* __restrict__ bsum, int nb)
{
    __shared__ int sh[256];
    int t = threadIdx.x;
    int v = (t < nb) ? bsum[t] : 0;
    sh[t] = v;
    __syncthreads();
    #pragma unroll
    for (int off = 1; off < 256; off <<= 1) {
        int u = (t >= off) ? sh[t - off] : 0;
        __syncthreads();
        sh[t] += u;
        __syncthreads();
    }
    if (t < nb) bsum[t] = sh[t] - v;   // exclusive
}

// K2c: rowptr + cursor + dinv = rsqrt(1+deg)
__global__ __launch_bounds__(256) void k_scan3(
    const int* __restrict__ counts, const int* __restrict__ bsum,
    int* __restrict__ rowptr, int* __restrict__ cursor,
    float* __restrict__ dinv, int n)
{
    __shared__ int sh[256];
    int t = threadIdx.x;
    int i = blockIdx.x * 256 + t;
    int v = (i < n) ? counts[i] : 0;
    sh[t] = v;
    __syncthreads();
    #pragma unroll
    for (int off = 1; off < 256; off <<= 1) {
        int u = (t >= off) ? sh[t - off] : 0;
        __syncthreads();
        sh[t] += u;
        __syncthreads();
    }
    if (i < n) {
        int excl = bsum[blockIdx.x] + sh[t] - v;
        rowptr[i] = excl;
        cursor[i] = excl;
        dinv[i] = rsqrtf((float)(1 + v));
        if (i == n - 1) rowptr[n] = excl + v;
    }
}

// K3: blocks [0,scatBlocks): CSR scatter (grid-stride, atomic cursor)
//     blocks [scatBlocks,..): MFMA GEMM halves -> interleaved bf16 pk + logits
// Each GEMM block: 64 rows x 128 cols (half=0 -> h / gat_W cols, half=1 ->
// g / gcn_W cols, pre-scaled by dinv). 32 KB LDS (XOR-swizzled Wt half).
// pk layout per row (256 u16): h pair p at {4p,4p+1}, g*dinv pair p at
// {4p+2,4p+3}; lane l of k_fused reads uint2 at row*64+l.
__global__ __launch_bounds__(256) void k_combo_scatter(
    const float* __restrict__ x, const unsigned short* __restrict__ wt,
    const float* __restrict__ att_src, const float* __restrict__ att_dst,
    const float* __restrict__ dinv, const int* __restrict__ src,
    const int* __restrict__ dst, int* __restrict__ cursor,
    int* __restrict__ esorted, unsigned short* __restrict__ pk,
    float* __restrict__ a_src, float* __restrict__ a_dst,
    int n, int E, int scatBlocks)
{
    __shared__ unsigned short wlds[16384];              // 32 KB
    const int t = threadIdx.x;

    if (blockIdx.x < scatBlocks) {
        int i = blockIdx.x * 256 + t;
        const int stride = scatBlocks * 256;
        for (; i < E; i += stride) {
            const int p = atomicAdd(&cursor[dst[i]], 1);
            esorted[p] = src[i];
        }
        return;
    }

    const int gb = blockIdx.x - scatBlocks;
    const int half = gb & 1;                  // 0: h cols / 1: g cols
    const int gtile = gb >> 1;

    // ---- stage this half's Wt rows -> LDS (swizzled) ----
    char* lbase = (char*)wlds;
    #pragma unroll
    for (int i2 = 0; i2 < 8; ++i2) {
        const int ch = i2 * 256 + t;                    // 16B chunk, 0..2047
        const int nn = ch >> 4;                         // local row 0..127
        const int off = (ch & 15) * 16;
        const int byte = (nn * 256 + off) ^ ((nn & 7) << 4);
        *reinterpret_cast<u16x8*>(lbase + byte) =
            *reinterpret_cast<const u16x8*>(
                wt + (size_t)(half * 128 + nn) * 128 + (ch & 15) * 8);
    }
    __syncthreads();

    const int l = t & 63;
    const int row0 = gtile * 64 + (t >> 6) * 16;        // wave's 16 rows
    const int arow = row0 + (l & 15);
    const bool av = arow < n;
    const float* xp = x + (size_t)arow * 128 + (l >> 4) * 8;

    // ---- A fragments straight from global (fp32 -> bf16 in-register) ----
    bf16x8 afr[4];
    #pragma unroll
    for (int ks = 0; ks < 4; ++ks) {
        float4 u0 = av ? *reinterpret_cast<const float4*>(xp + ks * 32)
                       : make_float4(0.f, 0.f, 0.f, 0.f);
        float4 u1 = av ? *reinterpret_cast<const float4*>(xp + ks * 32 + 4)
                       : make_float4(0.f, 0.f, 0.f, 0.f);
        bf16x8 a;
        a[0] = (short)f2bf(u0.x); a[1] = (short)f2bf(u0.y);
        a[2] = (short)f2bf(u0.z); a[3] = (short)f2bf(u0.w);
        a[4] = (short)f2bf(u1.x); a[5] = (short)f2bf(u1.y);
        a[6] = (short)f2bf(u1.z); a[7] = (short)f2bf(u1.w);
        afr[ks] = a;
    }

    // ---- MFMA: 8 N-tiles x 4 K-steps ----
    f32x4 acc[8];
    #pragma unroll
    for (int ni = 0; ni < 8; ++ni) acc[ni] = (f32x4){0.f, 0.f, 0.f, 0.f};

    const int bco = (l & 15) * 256 + (l >> 4) * 16;
    const int bxo = (l & 7) << 4;
    #pragma unroll
    for (int ks = 0; ks < 4; ++ks) {
        #pragma unroll
        for (int ni = 0; ni < 8; ++ni) {
            const int byte = ((ni * 16) * 256 + bco + ks * 64) ^ bxo;
            const bf16x8 b = *reinterpret_cast<const bf16x8*>(lbase + byte);
            acc[ni] = __builtin_amdgcn_mfma_f32_16x16x32_bf16(afr[ks], b, acc[ni], 0, 0, 0);
        }
    }

    const int m = l & 15;
    const int mo = m & 1;

    if (half == 0) {
        // ---- attention logits (h cols); C: col=ni*16+m, row=row0+(l>>4)*4+q
        float ps[4][4], pd[4][4];
        #pragma unroll
        for (int h = 0; h < 4; ++h)
            #pragma unroll
            for (int q = 0; q < 4; ++q) { ps[h][q] = 0.f; pd[h][q] = 0.f; }
        #pragma unroll
        for (int ni = 0; ni < 8; ++ni) {
            const float as = att_src[ni * 16 + m];
            const float ad = att_dst[ni * 16 + m];
            #pragma unroll
            for (int q = 0; q < 4; ++q) {
                ps[ni >> 1][q] += acc[ni][q] * as;
                pd[ni >> 1][q] += acc[ni][q] * ad;
            }
        }
        #pragma unroll
        for (int h = 0; h < 4; ++h) {
            #pragma unroll
            for (int q = 0; q < 4; ++q) {
                float v = ps[h][q];
                v += __shfl_xor(v, 1); v += __shfl_xor(v, 2);
                v += __shfl_xor(v, 4); v += __shfl_xor(v, 8);
                ps[h][q] = v;
                float u = pd[h][q];
                u += __shfl_xor(u, 1); u += __shfl_xor(u, 2);
                u += __shfl_xor(u, 4); u += __shfl_xor(u, 8);
                pd[h][q] = u;
            }
        }
        if (m == 0) {
            #pragma unroll
            for (int q = 0; q < 4; ++q) {
                const int row = row0 + (l >> 4) * 4 + q;
                if (row < n) {
                    *reinterpret_cast<float4*>(a_src + (size_t)row * 4) =
                        make_float4(ps[0][q], ps[1][q], ps[2][q], ps[3][q]);
                    *reinterpret_cast<float4*>(a_dst + (size_t)row * 4) =
                        make_float4(pd[0][q], pd[1][q], pd[2][q], pd[3][q]);
                }
            }
        }
        // ---- pack h ----
        #pragma unroll
        for (int q = 0; q < 4; ++q) {
            const int row = row0 + (l >> 4) * 4 + q;
            if (row >= n) continue;
            unsigned short* pr = pk + (size_t)row * 256;
            #pragma unroll
            for (int ni = 0; ni < 8; ++ni) {
                const int c = ni * 16 + m;
                pr[2 * c - mo] = f2bf(acc[ni][q]);
            }
        }
    } else {
        // ---- pack g * dinv ----
        #pragma unroll
        for (int q = 0; q < 4; ++q) {
            const int row = row0 + (l >> 4) * 4 + q;
            if (row >= n) continue;
            const float dv = dinv[row];
            unsigned short* pr = pk + (size_t)row * 256;
            #pragma unroll
            for (int ni = 0; ni < 8; ++ni) {
                const int cp = ni * 16 + m;
                pr[2 * cp + 2 - mo] = f2bf(acc[ni][q] * dv);
            }
        }
    }
}

// K4: single-pass gather (deferred softmax norm) + gate + residual + LN
// wave per node; lane owns channels {2l, 2l+1}; 4-way unroll.
__global__ __launch_bounds__(256) void k_fused(
    const int* __restrict__ esorted, const int* __restrict__ rowptr,
    const uint2* __restrict__ pkv,
    const float* __restrict__ a_src, const float* __restrict__ a_dst,
    const float* __restrict__ dinv, const float* __restrict__ x,
    const float* __restrict__ gat_bias, const float* __restrict__ gcn_bias,
    const float* __restrict__ gate_W, const float* __restrict__ gate_b,
    const float* __restrict__ gamma, const float* __restrict__ beta,
    float* __restrict__ out, int n)
{
    const int lane = threadIdx.x & 63;
    const int node = blockIdx.x * 4 + (threadIdx.x >> 6);
    if (node >= n) return;

    const int head = lane >> 4;
    const float adh = a_dst[node * 4 + head];
    const int beg = rowptr[node], end = rowptr[node + 1];

    float acc0 = 0.f, acc1 = 0.f, accg0 = 0.f, accg1 = 0.f, ws = 0.f;

#define ELOAD(i) \
    const int s##i = esorted[j + i]; \
    const uint2 f##i = pkv[(size_t)s##i * 64 + lane]; \
    const float a##i = a_src[s##i * 4 + head];

#define EBODY(i) \
    { \
        float e = a##i + adh; e = e > 0.f ? e : 0.2f * e; \
        const float w = __expf(e); ws += w; \
        acc0  = fmaf(w, bflo(f##i.x), acc0); \
        acc1  = fmaf(w, bfhi(f##i.x), acc1); \
        accg0 += bflo(f##i.y); \
        accg1 += bfhi(f##i.y); \
    }

    int j = beg;
    for (; j + 4 <= end; j += 4) {
        ELOAD(0) ELOAD(1) ELOAD(2) ELOAD(3)
        EBODY(0) EBODY(1) EBODY(2) EBODY(3)
    }
    for (; j < end; ++j) {
        ELOAD(0)
        EBODY(0)
    }

    // self loop
    {
        const uint2 f = pkv[(size_t)node * 64 + lane];
        float e = a_src[node * 4 + head] + adh;
        e = e > 0.f ? e : 0.2f * e;
        const float w = __expf(e);
        ws += w;
        acc0  = fmaf(w, bflo(f.x), acc0);
        acc1  = fmaf(w, bfhi(f.x), acc1);
        accg0 += bflo(f.y);
        accg1 += bfhi(f.y);
    }
#undef ELOAD
#undef EBODY

    // ---- epilogue: gate softmax + fuse + residual + LayerNorm ----
    const float dvd = dinv[node];
    const float2 gb2 = *reinterpret_cast<const float2*>(gat_bias + 2 * lane);
    const float2 gc2 = *reinterpret_cast<const float2*>(gcn_bias + 2 * lane);
    const float iws = 1.f / ws;
    float ga0 = acc0 * iws + gb2.x;
    float ga1 = acc1 * iws + gb2.y;
    float gc0 = accg0 * dvd + gc2.x;
    float gc1 = accg1 * dvd + gc2.y;

    const float4 gwa = *reinterpret_cast<const float4*>(gate_W + 4 * lane);
    const float4 gwb = *reinterpret_cast<const float4*>(gate_W + 256 + 4 * lane);
    float z0 = ga0 * gwa.x + ga1 * gwa.z + gc0 * gwb.x + gc1 * gwb.z;
    float z1 = ga0 * gwa.y + ga1 * gwa.w + gc0 * gwb.y + gc1 * gwb.w;
    #pragma unroll
    for (int off = 32; off >= 1; off >>= 1) {
        z0 += __shfl_xor(z0, off);
        z1 += __shfl_xor(z1, off);
    }
    z0 += gate_b[0]; z1 += gate_b[1];
    float m = fmaxf(z0, z1);
    float ez0 = __expf(z0 - m), ez1 = __expf(z1 - m);
    float inv = 1.f / (ez0 + ez1);
    float g0 = ez0 * inv, g1 = ez1 * inv;

    const size_t nbase = (size_t)node * 128;
    const float2 xv = *reinterpret_cast<const float2*>(x + nbase + 2 * lane);
    float y0 = g0 * ga0 + g1 * gc0 + xv.x;
    float y1 = g0 * ga1 + g1 * gc1 + xv.y;

    float sum = y0 + y1;
    #pragma unroll
    for (int off = 32; off >= 1; off >>= 1) sum += __shfl_xor(sum, off);
    float mu = sum * (1.f / 128.f);
    float d0v = y0 - mu, d1v = y1 - mu;
    float sq = d0v * d0v + d1v * d1v;
    #pragma unroll
    for (int off = 32; off >= 1; off >>= 1) sq += __shfl_xor(sq, off);
    float r = rsqrtf(sq * (1.f / 128.f) + 1e-5f);

    const float2 gm = *reinterpret_cast<const float2*>(gamma + 2 * lane);
    const float2 bt = *reinterpret_cast<const float2*>(beta + 2 * lane);
    float2 o;
    o.x = d0v * r * gm.x + bt.x;
    o.y = d1v * r * gm.y + bt.y;
    *reinterpret_cast<float2*>(out + nbase + 2 * lane) = o;
}

extern "C" void kernel_launch(void* const* d_in, const int* in_sizes, int n_in,
                              void* d_out, int out_size, void* d_ws, size_t ws_size,
                              hipStream_t stream)
{
    const float* x        = (const float*)d_in[0];
    const float* gat_W    = (const float*)d_in[1];
    const float* att_src  = (const float*)d_in[2];
    const float* att_dst  = (const float*)d_in[3];
    const float* gat_bias = (const float*)d_in[4];
    const float* gcn_W    = (const float*)d_in[5];
    const float* gcn_bias = (const float*)d_in[6];
    const float* gate_W   = (const float*)d_in[7];
    const float* gate_b   = (const float*)d_in[8];
    const float* ln_gamma = (const float*)d_in[9];
    const float* ln_beta  = (const float*)d_in[10];
    const int*   edge     = (const int*)d_in[11];

    const int n = in_sizes[0] / 128;
    const int E = in_sizes[11] / 2;
    const int* src = edge;
    const int* dst = edge + E;
    const int nb_chunks = (n + 255) / 256;   // 196 for n=50000 (<=256 required)

    char* w = (char*)d_ws;
    unsigned short* pk = (unsigned short*)w;  w += (size_t)n * 256 * 2;
    unsigned short* wt = (unsigned short*)w;  w += (size_t)256 * 128 * 2;
    float* a_src   = (float*)w;  w += (size_t)n * 4 * 4;
    float* a_dst   = (float*)w;  w += (size_t)n * 4 * 4;
    float* dinv    = (float*)w;  w += (size_t)n * 4;
    int*   counts  = (int*)w;    w += (size_t)n * 4;
    int*   bsum    = (int*)w;    w += (size_t)256 * 4;
    int*   rowptr  = (int*)w;    w += (size_t)(n + 1) * 4;
    int*   cursor  = (int*)w;    w += (size_t)n * 4;
    int*   esorted = (int*)w;    w += (size_t)E * 4;

    hipMemsetAsync(counts, 0, (size_t)n * 4, stream);

    const int histBlocks = 1024;
    const int scatBlocks = 1024;
    const int gemmBlocks = 2 * ((n + 63) / 64);     // 1564 half-blocks

    k_prep_hist<<<16 + histBlocks, 256, 0, stream>>>(gat_W, gcn_W, wt, dst, counts, E);
    k_scan1<<<nb_chunks, 256, 0, stream>>>(counts, bsum, n);
    k_scan2<<<1, 256, 0, stream>>>(bsum, nb_chunks);
    k_scan3<<<nb_chunks, 256, 0, stream>>>(counts, bsum, rowptr, cursor, dinv, n);
    k_combo_scatter<<<scatBlocks + gemmBlocks, 256, 0, stream>>>(
        x, wt, att_src, att_dst, dinv, src, dst, cursor, esorted,
        pk, a_src, a_dst, n, E, scatBlocks);
    k_fused<<<(n + 3) / 4, 256, 0, stream>>>(esorted, rowptr, (const uint2*)pk,
                                             a_src, a_dst, dinv, x, gat_bias, gcn_bias,
                                             gate_W, gate_b, ln_gamma, ln_beta,
                                             (float*)d_out, n);
}